// Round 4
// baseline (662.018 us; speedup 1.0000x reference)
//
#include <hip/hip_runtime.h>
#include <cmath>
#include <utility>

// SSIM + L1 image similarity loss, MI355X (gfx950).
// es, ta: fp32 [16,3,512,512]. Output: out[0]=l1_loss, out[1]=ssim_loss.
//
// R4: R2/R3 showed VGPR=40 + scratch traffic -> the compiler rolled the
// stream loop and sent the accumulator arrays to local memory (rule #20).
// Fixes:
//  - template-forced full unroll (integer_sequence + if constexpr): every
//    accumulator index is a compile-time constant BY CONSTRUCTION.
//  - first-touch assign + early per-row finalize: peak live set ~60 VGPR.
//  - __launch_bounds__(256,4): VGPR cap 128 (no heuristic strangling).
//  - float2 {e,t} interleaved LDS tile: 11x ds_read_b64 (8B-aligned,
//    conflict-free, offset-immediate addressed) instead of 22x b32.

constexpr int TILE_W = 64;
constexpr int TILE_H = 32;
constexpr int HALO = 5;
constexpr int WIN  = 11;
constexpr int LH   = TILE_H + 2 * HALO;  // 42 staged rows
constexpr int LW   = TILE_W + 2 * HALO;  // 74 staged cols
constexpr int LSTR = 76;                 // LDS row stride (float2 units)
constexpr int IMG  = 512;
constexpr int ROWS_PER_WAVE = 8;         // 4 waves x 8 rows = 32
constexpr int STREAM_ROWS = ROWS_PER_WAVE + WIN - 1;  // 18
constexpr float C1C = 0.01f * 0.01f;
constexpr float C2C = 0.03f * 0.03f;

struct Wnd { float g[WIN]; };

template<class F, int... I>
__device__ inline void unroll_impl(F&& f, std::integer_sequence<int, I...>) {
    (f(std::integral_constant<int, I>{}), ...);
}
template<int N, class F>
__device__ inline void s_unroll(F&& f) {
    unroll_impl(static_cast<F&&>(f), std::make_integer_sequence<int, N>{});
}

__global__ __launch_bounds__(256, 4) void ssim_main(
    const float* __restrict__ es, const float* __restrict__ ta,
    float* __restrict__ accbuf, Wnd w)
{
    __shared__ float2 sS[LH * LSTR];

    const int tid = threadIdx.x;
    const int tx0 = blockIdx.x * TILE_W;
    const int ty0 = blockIdx.y * TILE_H;
    const int img = blockIdx.z;
    const float* pe = es + (size_t)img * (IMG * IMG);
    const float* pt = ta + (size_t)img * (IMG * IMG);

    // ---- stage interleaved {e,t} tile (zero-pad outside image) ----
    for (int i = tid; i < LH * LW; i += 256) {
        int r = i / LW;
        int c = i - r * LW;
        int gy = ty0 - HALO + r;
        int gx = tx0 - HALO + c;
        float ev = 0.f, tv = 0.f;
        if (gy >= 0 && gy < IMG && gx >= 0 && gx < IMG) {
            int off = gy * IMG + gx;
            ev = pe[off];
            tv = pt[off];
        }
        sS[r * LSTR + c] = make_float2(ev, tv);
    }
    __syncthreads();

    const int wv = tid >> 6;   // wave id 0..3 -> 8-row segment
    const int ln = tid & 63;   // lane -> column
    const int rbase = wv * ROWS_PER_WAVE;
    const float2* rp = &sS[rbase * LSTR + ln];  // one base addr; rest immediates

    float a0[ROWS_PER_WAVE], a1[ROWS_PER_WAVE], a2[ROWS_PER_WAVE],
          a3[ROWS_PER_WAVE], a4[ROWS_PER_WAVE];
    float ssim_s = 0.f, l1_s = 0.f;

    s_unroll<STREAM_ROWS>([&](auto rrc) {
        constexpr int rr = decltype(rrc)::value;

        // horizontal 11-tap of {e, t, e^2, t^2, e*t} for streamed row rr
        float hm1 = 0.f, hm2 = 0.f, h11 = 0.f, h22 = 0.f, h12 = 0.f;
        s_unroll<WIN>([&](auto kc) {
            constexpr int k = decltype(kc)::value;
            float2 v = rp[rr * LSTR + k];       // ds_read_b64, imm offset
            float gk = w.g[k];
            float ge = gk * v.x;
            float gt = gk * v.y;
            hm1 += ge;
            hm2 += gt;
            h11 += ge * v.x;
            h22 += gt * v.y;
            h12 += ge * v.y;
        });

        // vertical scatter: streamed row rr feeds output rows rr-10..rr
        s_unroll<WIN>([&](auto kc) {
            constexpr int k = decltype(kc)::value;
            constexpr int o = rr - k;
            if constexpr (o >= 0 && o < ROWS_PER_WAVE) {
                float gk = w.g[k];
                if constexpr (k == 0) {         // first touch of row o
                    a0[o] = gk * hm1;
                    a1[o] = gk * hm2;
                    a2[o] = gk * h11;
                    a3[o] = gk * h22;
                    a4[o] = gk * h12;
                } else {
                    a0[o] += gk * hm1;
                    a1[o] += gk * hm2;
                    a2[o] += gk * h11;
                    a3[o] += gk * h22;
                    a4[o] += gk * h12;
                }
            }
        });

        // early finalize: output row o = rr-10 is complete; free its regs
        if constexpr (rr >= WIN - 1) {
            constexpr int o = rr - (WIN - 1);
            float mu1 = a0[o], mu2 = a1[o];
            float m11 = mu1 * mu1, m22 = mu2 * mu2, m12 = mu1 * mu2;
            float s11 = a2[o] - m11;
            float s22 = a3[o] - m22;
            float s12 = a4[o] - m12;
            float num = (2.f * m12 + C1C) * (2.f * s12 + C2C);
            float den = (m11 + m22 + C1C) * (s11 + s22 + C2C);
            ssim_s += num * __builtin_amdgcn_rcpf(den);

            float2 c = rp[(o + HALO) * LSTR + HALO];  // center pixel {e,t}
            l1_s += fabsf(c.x - c.y);
        }
    });

    // ---- wave reduce + one atomic pair per wave ----
    #pragma unroll
    for (int off = 32; off >= 1; off >>= 1) {
        ssim_s += __shfl_xor(ssim_s, off, 64);
        l1_s   += __shfl_xor(l1_s, off, 64);
    }
    if (ln == 0) {
        atomicAdd(&accbuf[0], ssim_s);
        atomicAdd(&accbuf[1], l1_s);
    }
}

__global__ void ssim_finalize(const float* __restrict__ acc, float* __restrict__ out)
{
    const float N = 16.f * 3.f * 512.f * 512.f;
    out[0] = 0.15f * (acc[1] / N);
    out[1] = 0.85f * 0.5f * (1.f - acc[0] / N);
}

extern "C" void kernel_launch(void* const* d_in, const int* in_sizes, int n_in,
                              void* d_out, int out_size, void* d_ws, size_t ws_size,
                              hipStream_t stream)
{
    const float* es = (const float*)d_in[0];
    const float* ta = (const float*)d_in[1];
    float* out = (float*)d_out;
    float* acc = (float*)d_ws;

    hipMemsetAsync(acc, 0, 2 * sizeof(float), stream);

    Wnd w;
    double gd[WIN], sum = 0.0;
    for (int i = 0; i < WIN; ++i) {
        double x = (double)(i - WIN / 2);
        gd[i] = std::exp(-(x * x) / (2.0 * 1.5 * 1.5));
        sum += gd[i];
    }
    for (int i = 0; i < WIN; ++i) w.g[i] = (float)(gd[i] / sum);

    const int nimg = in_sizes[0] / (IMG * IMG);  // 16*3 = 48
    dim3 grid(IMG / TILE_W, IMG / TILE_H, nimg);
    ssim_main<<<grid, 256, 0, stream>>>(es, ta, acc, w);
    ssim_finalize<<<1, 1, 0, stream>>>(acc, out);
}